// Round 4
// baseline (286.532 us; speedup 1.0000x reference)
//
#include <hip/hip_runtime.h>

#define NF      100
#define BLOCK   128
#define TILE    64                  // rows per tile
#define F4T     (TILE * 25)         // 1600 float4 = 25.6 KB of real data per tile
#define NLD     13                  // staging issues per wave, ALWAYS 13 (uniform vmcnt)
#define F4PAD   (NLD * BLOCK)       // 1664: buffer padded so issue 12's tail is contained
#define NBUF    3
#define MAXGRID 512                 // 2 blocks/CU; LDS = 3*26.6 + 0.8 = 80.7 KB <= 80 KiB

// Wave-uniform staging: every wave issues exactly NLD global_load_lds (vmcnt
// accounting depends on this). Per-lane SOURCE is clamped into range; DEST
// runs 0..F4PAD-1 inside the padded buffer (fixes round-3's 64-float4 overrun
// into the adjacent buffer). Dest keeps the required base + lane*16 pattern.
__device__ __forceinline__ void stage_tile(const float4* __restrict__ x4,
                                           float4* dst, int f4base, int maxf4,
                                           int tid) {
#pragma unroll
  for (int u = 0; u < NLD; ++u) {
    int g = f4base + u * BLOCK + tid;
    g = g > maxf4 ? maxf4 : g;
    __builtin_amdgcn_global_load_lds(
        (const __attribute__((address_space(1))) void*)(x4 + g),
        (__attribute__((address_space(3))) void*)(dst + u * BLOCK + tid),
        16, 0, 0);
  }
}

// s_waitcnt imm (gfx9 encoding): vmcnt[3:0]@[3:0], expcnt@[6:4], lgkmcnt@[11:8],
// vmcnt[5:4]@[15:14].  0x007D = vmcnt(13), expcnt(7)=no-wait, lgkmcnt(0).
#define WAITCNT_VM13_LGKM0 0x007D

__global__ __launch_bounds__(BLOCK, 1) void fused_kernel(
    const float4* __restrict__ x4,
    const float* __restrict__ A_real, const float* __restrict__ A_imag,
    const float* __restrict__ psi_real, const float* __restrict__ psi_imag,
    float2* __restrict__ out, int batch, int ntiles) {
  __shared__ float4 xs[NBUF][F4PAD];         // padded buffers
  __shared__ __align__(16) float2 msl[NF];   // (M_re[0,a], M_re[1,a]) per feature

  const int tid = threadIdx.x;

  // ---- Phase 1 (per-block, redundant): M_re[k,a] from psi & A (160 KB, L2/L3-hot)
  if (tid < NF) {
    const int a = tid;
    float pr[10], pi[10];
#pragma unroll
    for (int i = 0; i < 10; ++i) { pr[i] = psi_real[i]; pi[i] = psi_imag[i]; }
    float m0 = 0.f, m1 = 0.f;
#pragma unroll
    for (int i = 0; i < 10; ++i) {
#pragma unroll
      for (int j = 0; j < 10; ++j) {
        float pre = pr[i] * pr[j] + pi[i] * pi[j];
        float pim = pr[i] * pi[j] - pi[i] * pr[j];
        int off = (i * 10 + j) * NF + a;          // k=0
        m0 = fmaf(pre, A_real[off], m0);
        m0 = fmaf(-pim, A_imag[off], m0);
        m1 = fmaf(pre, A_real[off + 10000], m1);  // k=1
        m1 = fmaf(-pim, A_imag[off + 10000], m1);
      }
    }
    msl[a] = make_float2(m0, m1);
  }
  __syncthreads();  // full drain fine here: no staging in flight yet

  // ---- M half into registers: 26 float4 = features [48h, 48h+52) interleaved
  const int h = tid & 1;    // which half of the 100 features
  const int r = tid >> 1;   // row within tile (0..63)
  const float4* msl4 = (const float4*)msl;
  float4 mreg[26];
#pragma unroll
  for (int j = 0; j < 26; ++j) mreg[j] = msl4[24 * h + j];

  // ---- Phase 2: persistent triple-buffered stream over tiles
  const int maxf4 = batch * 25 - 1;
  const int stride = gridDim.x;

  float4* b0 = &xs[0][0];
  float4* b1 = &xs[1][0];
  float4* b2 = &xs[2][0];

  int t = blockIdx.x;
  stage_tile(x4, b0, t * F4T, maxf4, tid);             // tile t
  stage_tile(x4, b1, (t + stride) * F4T, maxf4, tid);  // tile t+stride

  for (; t < ntiles; t += stride) {
    // Wait for the OLDEST stage (this tile) only; the next tile's 13 loads
    // (and the output stores) stay in flight across the barrier.
    __builtin_amdgcn_s_waitcnt(WAITCNT_VM13_LGKM0);
    __builtin_amdgcn_s_barrier();

    stage_tile(x4, b2, (t + 2 * stride) * F4T, maxf4, tid);  // reuse oldest buf

    const float4* xrow = b0 + r * 25 + (h ? 12 : 0);  // h0: chunks 0..11, h1: 12..24
    float a0 = 0.f, a1 = 0.f;
#pragma unroll
    for (int j = 0; j < 13; ++j) {
      if (j < 12 + h) {
        float4 xv = xrow[j];
        float4 mA = mreg[2 * j];      // features f,f+1 as (m0,m1,m0,m1)
        float4 mB = mreg[2 * j + 1];  // features f+2,f+3
        a0 = fmaf(xv.x, mA.x, a0); a1 = fmaf(xv.x, mA.y, a1);
        a0 = fmaf(xv.y, mA.z, a0); a1 = fmaf(xv.y, mA.w, a1);
        a0 = fmaf(xv.z, mB.x, a0); a1 = fmaf(xv.z, mB.y, a1);
        a0 = fmaf(xv.w, mB.z, a0); a1 = fmaf(xv.w, mB.w, a1);
      }
    }
    a0 += __shfl_xor(a0, 1);
    a1 += __shfl_xor(a1, 1);
    const int t0 = t * TILE;
    if (h == 0 && r < batch - t0) out[t0 + r] = make_float2(a0, a1);

    float4* tmp = b0; b0 = b1; b1 = b2; b2 = tmp;
  }
}

extern "C" void kernel_launch(void* const* d_in, const int* in_sizes, int n_in,
                              void* d_out, int out_size, void* d_ws, size_t ws_size,
                              hipStream_t stream) {
  const float* x  = (const float*)d_in[0];
  const float* Ar = (const float*)d_in[1];
  const float* Ai = (const float*)d_in[2];
  const float* pr = (const float*)d_in[3];
  const float* pi = (const float*)d_in[4];
  const int batch = in_sizes[0] / NF;

  const int ntiles = (batch + TILE - 1) / TILE;
  const int grid = ntiles < MAXGRID ? ntiles : MAXGRID;
  fused_kernel<<<grid, BLOCK, 0, stream>>>(
      (const float4*)x, Ar, Ai, pr, pi, (float2*)d_out, batch, ntiles);
}

// Round 5
// 282.894 us; speedup vs baseline: 1.0129x; 1.0129x over previous
//
#include <hip/hip_runtime.h>

#define NF      100
#define BLOCK   128
#define TILE    64                  // rows per tile
#define F4T     (TILE * 25)         // 1600 float4 = 25.6 KB of real data per tile
#define NLD     13                  // staging issues per wave, ALWAYS 13 (uniform vmcnt)
#define F4PAD   (NLD * BLOCK)       // 1664: padded so issue 12's tail is contained
#define NBUF    3
#define MAXGRID 512                 // 2 blocks/CU; LDS = 3*26.6 + 0.8 = 78.8 KiB

// Wave-uniform staging: every wave issues exactly NLD global_load_lds. Per-lane
// SOURCE clamped in range; DEST = base + lane*16 over the padded buffer.
__device__ __forceinline__ void stage_tile(const float4* __restrict__ x4,
                                           float4* dst, int f4base, int maxf4,
                                           int tid) {
#pragma unroll
  for (int u = 0; u < NLD; ++u) {
    int g = f4base + u * BLOCK + tid;
    g = g > maxf4 ? maxf4 : g;
    __builtin_amdgcn_global_load_lds(
        (const __attribute__((address_space(1))) void*)(x4 + g),
        (__attribute__((address_space(3))) void*)(dst + u * BLOCK + tid),
        16, 0, 0);
  }
}

// s_waitcnt imm: vmcnt[3:0]@[3:0], expcnt@[6:4], lgkmcnt@[11:8], vmcnt[5:4]@[15:14]
// 0x007E = vmcnt(14), expcnt(7)=no-wait, lgkmcnt(0).
// FIFO at loop-top wait: [S_k remnant(12-13), store(1), S_{k+1} x13] -> draining
// to 14 retires exactly S_k + old store, never the in-flight next stage.
#define WAITCNT_VM14_LGKM0 0x007E

__global__ __launch_bounds__(BLOCK, 1) void fused_kernel(
    const float4* __restrict__ x4,
    const float* __restrict__ A_real, const float* __restrict__ A_imag,
    const float* __restrict__ psi_real, const float* __restrict__ psi_imag,
    float2* __restrict__ out, int batch, int ntiles) {
  __shared__ float4 xs[NBUF][F4PAD];         // padded buffers
  __shared__ __align__(16) float2 msl[NF];   // (M_re[0,a], M_re[1,a]) per feature

  const int tid = threadIdx.x;
  const int maxf4 = batch * 25 - 1;
  const int stride = gridDim.x;

  float4* b0 = &xs[0][0];
  float4* b1 = &xs[1][0];
  float4* b2 = &xs[2][0];

  // ---- Start the x stream IMMEDIATELY (before the M-phase dependency chain),
  // so HBM is busy from cycle ~0 instead of after ~3 us of A-loads.
  int t = blockIdx.x;
  stage_tile(x4, b0, t * F4T, maxf4, tid);             // tile t
  stage_tile(x4, b1, (t + stride) * F4T, maxf4, tid);  // tile t+stride

  // ---- Phase 1 (per-block, redundant): M_re[k,a] from psi & A (160 KB, L2-hot)
  if (tid < NF) {
    const int a = tid;
    float pr[10], pi[10];
#pragma unroll
    for (int i = 0; i < 10; ++i) { pr[i] = psi_real[i]; pi[i] = psi_imag[i]; }
    float m0 = 0.f, m1 = 0.f;
#pragma unroll
    for (int i = 0; i < 10; ++i) {
#pragma unroll
      for (int j = 0; j < 10; ++j) {
        float pre = pr[i] * pr[j] + pi[i] * pi[j];
        float pim = pr[i] * pi[j] - pi[i] * pr[j];
        int off = (i * 10 + j) * NF + a;          // k=0
        m0 = fmaf(pre, A_real[off], m0);
        m0 = fmaf(-pim, A_imag[off], m0);
        m1 = fmaf(pre, A_real[off + 10000], m1);  // k=1
        m1 = fmaf(-pim, A_imag[off + 10000], m1);
      }
    }
    msl[a] = make_float2(m0, m1);
  }
  // One-time full drain (vmcnt(0) implied by syncthreads): S_0 and S_s land
  // here; they were issued at cycle ~0 so most latency is already hidden.
  __syncthreads();

  // ---- M half into registers: 26 float4 = features [48h, 48h+52) interleaved
  const int h = tid & 1;    // which half of the 100 features
  const int r = tid >> 1;   // row within tile (0..63)
  const float4* msl4 = (const float4*)msl;
  float4 mreg[26];
#pragma unroll
  for (int j = 0; j < 26; ++j) mreg[j] = msl4[24 * h + j];

  // ---- Phase 2: persistent triple-buffered stream over tiles
  for (; t < ntiles; t += stride) {
    // Drain exactly this tile's stage (+ the 2-iterations-old store); the
    // next tile's 13 loads stay in flight across the barrier.
    __builtin_amdgcn_s_waitcnt(WAITCNT_VM14_LGKM0);
    __builtin_amdgcn_s_barrier();

    stage_tile(x4, b2, (t + 2 * stride) * F4T, maxf4, tid);  // reuse oldest buf

    const float4* xrow = b0 + r * 25 + (h ? 12 : 0);  // h0: chunks 0..11, h1: 12..24
    float a0 = 0.f, a1 = 0.f;
#pragma unroll
    for (int j = 0; j < 13; ++j) {
      if (j < 12 + h) {
        float4 xv = xrow[j];
        float4 mA = mreg[2 * j];      // features f,f+1 as (m0,m1,m0,m1)
        float4 mB = mreg[2 * j + 1];  // features f+2,f+3
        a0 = fmaf(xv.x, mA.x, a0); a1 = fmaf(xv.x, mA.y, a1);
        a0 = fmaf(xv.y, mA.z, a0); a1 = fmaf(xv.y, mA.w, a1);
        a0 = fmaf(xv.z, mB.x, a0); a1 = fmaf(xv.z, mB.y, a1);
        a0 = fmaf(xv.w, mB.z, a0); a1 = fmaf(xv.w, mB.w, a1);
      }
    }
    a0 += __shfl_xor(a0, 1);
    a1 += __shfl_xor(a1, 1);
    const int t0 = t * TILE;
    if (h == 0 && r < batch - t0) out[t0 + r] = make_float2(a0, a1);

    float4* tmp = b0; b0 = b1; b1 = b2; b2 = tmp;
  }
}

extern "C" void kernel_launch(void* const* d_in, const int* in_sizes, int n_in,
                              void* d_out, int out_size, void* d_ws, size_t ws_size,
                              hipStream_t stream) {
  const float* x  = (const float*)d_in[0];
  const float* Ar = (const float*)d_in[1];
  const float* Ai = (const float*)d_in[2];
  const float* pr = (const float*)d_in[3];
  const float* pi = (const float*)d_in[4];
  const int batch = in_sizes[0] / NF;

  const int ntiles = (batch + TILE - 1) / TILE;
  const int grid = ntiles < MAXGRID ? ntiles : MAXGRID;
  fused_kernel<<<grid, BLOCK, 0, stream>>>(
      (const float4*)x, Ar, Ai, pr, pi, (float2*)d_out, batch, ntiles);
}